// Round 7
// baseline (482.336 us; speedup 1.0000x reference)
//
#include <hip/hip_runtime.h>
#include <hip/hip_bf16.h>
#include <math.h>

#define IN_CH 128
#define HID 64
#define HEADS 4
#define C1 (HEADS*HID)   // 256
#define OUT_CH 64

typedef __attribute__((ext_vector_type(8))) short short8v;
typedef __attribute__((ext_vector_type(4))) float f32x4;

__device__ __forceinline__ float lrelu(float x){ return x > 0.f ? x : 0.2f*x; }

__device__ __forceinline__ ushort f2b(float f){
  unsigned u = __builtin_bit_cast(unsigned, f);
  unsigned r = (u + 0x7FFF + ((u>>16)&1)) >> 16;
  return (ushort)r;
}
__device__ __forceinline__ float b2f(ushort b){
  unsigned u = ((unsigned)b) << 16;
  return __builtin_bit_cast(float, u);
}

__device__ __forceinline__ float wsum64(float v){
  #pragma unroll
  for (int m = 32; m >= 1; m >>= 1) v += __shfl_xor(v, m, 64);
  return v;
}
__device__ __forceinline__ float wmax64(float v){
  #pragma unroll
  for (int m = 32; m >= 1; m >>= 1) v = fmaxf(v, __shfl_xor(v, m, 64));
  return v;
}

// ---------------- CSR build (self-loops included as slots) ----------------

__global__ void k_init(int* deg, int* cur, int n){
  int i = blockIdx.x*256 + threadIdx.x;
  if (i < n){ deg[i] = 1; cur[i] = 0; }   // deg starts at 1: self-loop slot
}

__global__ void k_hist(const int* __restrict__ dst, int* deg, int e){
  int i = blockIdx.x*256 + threadIdx.x;
  if (i < e) atomicAdd(&deg[dst[i]], 1);
}

__global__ void k_blocksum(const int* __restrict__ deg, int* bsum, int n){
  __shared__ int buf[256];
  int b = blockIdx.x, tid = threadIdx.x;
  int i = b*256 + tid;
  buf[tid] = (i < n) ? deg[i] : 0;
  __syncthreads();
  for (int off = 128; off > 0; off >>= 1){
    if (tid < off) buf[tid] += buf[tid + off];
    __syncthreads();
  }
  if (tid == 0) bsum[b] = buf[0];
}

__global__ void k_scanb(int* bsum, int nb){
  __shared__ int buf[256];
  int tid = threadIdx.x;
  int v = (tid < nb) ? bsum[tid] : 0;
  buf[tid] = v;
  __syncthreads();
  for (int off = 1; off < 256; off <<= 1){
    int t = (tid >= off) ? buf[tid - off] : 0;
    __syncthreads();
    buf[tid] += t;
    __syncthreads();
  }
  if (tid < nb) bsum[tid] = buf[tid] - v;
}

__global__ void k_scanfinal(const int* __restrict__ deg, const int* __restrict__ bsum,
                            int* rowptr, int n){
  __shared__ int buf[256];
  int b = blockIdx.x, tid = threadIdx.x;
  int i = b*256 + tid;
  int v = (i < n) ? deg[i] : 0;
  buf[tid] = v;
  __syncthreads();
  for (int off = 1; off < 256; off <<= 1){
    int t = (tid >= off) ? buf[tid - off] : 0;
    __syncthreads();
    buf[tid] += t;
    __syncthreads();
  }
  if (i < n) rowptr[i + 1] = bsum[b] + buf[tid];
  if (b == 0 && tid == 0) rowptr[0] = 0;
}

__global__ void k_scatter(const int* __restrict__ src, const int* __restrict__ dst,
                          const int* __restrict__ rowptr, int* cursor, int* csrc, int e){
  int i = blockIdx.x*256 + threadIdx.x;
  if (i < e){
    int d = dst[i];
    int slot = rowptr[d] + atomicAdd(&cursor[d], 1);
    csrc[slot] = src[i];
  }
}

__global__ void k_self(const int* __restrict__ rowptr, int* csrc, int n){
  int i = blockIdx.x*256 + threadIdx.x;
  if (i < n) csrc[rowptr[i+1] - 1] = i;   // self-loop in last slot
}

// ---------------- weight folds ----------------

// W [K][N] f32 -> Wt [N][K] bf16
__global__ void k_tw(const float* __restrict__ W, ushort* __restrict__ Wt, int K, int N){
  int i = blockIdx.x*256 + threadIdx.x;
  if (i < K*N){
    int k = i / N, c = i - k*N;
    Wt[(size_t)c*K + k] = f2b(W[i]);
  }
}

__global__ void k_fold1(const float* __restrict__ W1, const float* __restrict__ as_v,
                        const float* __restrict__ ad_v, float* was4, float* wad4){
  int tid = threadIdx.x;           // 0..511 = c*4+h
  int c = tid >> 2, h = tid & 3;
  float s = 0.f, d = 0.f;
  for (int j = 0; j < HID; ++j){
    float w = W1[c*C1 + h*HID + j];
    s += w * as_v[h*HID + j];
    d += w * ad_v[h*HID + j];
  }
  was4[tid] = s; wad4[tid] = d;
}

__global__ void k_fold2(const float* __restrict__ W2, const float* __restrict__ as_v,
                        const float* __restrict__ ad_v, float* w2s, float* w2d){
  int c = threadIdx.x;             // 0..255
  float s = 0.f, d = 0.f;
  for (int o = 0; o < OUT_CH; ++o){
    float w = W2[c*OUT_CH + o];
    s += w * as_v[o];
    d += w * ad_v[o];
  }
  w2s[c] = s; w2d[c] = d;
}

// fused: cast x->bf16 + conv1 attention scores. wave per node, lane = 2 channels.
__global__ __launch_bounds__(64) void k_fattc(const float* __restrict__ x,
    const float* __restrict__ was4, const float* __restrict__ wad4,
    ushort* __restrict__ xb, float* __restrict__ as1, float* __restrict__ ad1, int n){
  int i = blockIdx.x;
  int l = threadIdx.x;
  float2 u = *(const float2*)(x + (size_t)i*IN_CH + 2*l);
  ushort2 o; o.x = f2b(u.x); o.y = f2b(u.y);
  *(ushort2*)(xb + (size_t)i*IN_CH + 2*l) = o;
  float v0 = u.x, v1 = u.y;
  f32x4 s0 = *(const f32x4*)(was4 + 8*l);
  f32x4 s1 = *(const f32x4*)(was4 + 8*l + 4);
  f32x4 d0 = *(const f32x4*)(wad4 + 8*l);
  f32x4 d1 = *(const f32x4*)(wad4 + 8*l + 4);
  f32x4 ps, pd;
  #pragma unroll
  for (int h = 0; h < 4; ++h){
    ps[h] = wsum64(v0*s0[h] + v1*s1[h]);
    pd[h] = wsum64(v0*d0[h] + v1*d1[h]);
  }
  if (l == 0){
    *(f32x4*)(as1 + 4*i) = ps;
    *(f32x4*)(ad1 + 4*i) = pd;
  }
}

// as2/ad2 from z1: wave per node, lane = 4 channels
__global__ __launch_bounds__(64) void k_fatt2(const ushort* __restrict__ z1b,
    const float* __restrict__ w2s, const float* __restrict__ w2d,
    float* __restrict__ as2, float* __restrict__ ad2, int n){
  int i = blockIdx.x;
  int l = threadIdx.x;
  ushort4 u = *(const ushort4*)(z1b + (size_t)i*C1 + 4*l);
  float v0 = b2f(u.x), v1 = b2f(u.y), v2 = b2f(u.z), v3 = b2f(u.w);
  f32x4 s = *(const f32x4*)(w2s + 4*l);
  f32x4 d = *(const f32x4*)(w2d + 4*l);
  float ps = wsum64(v0*s[0] + v1*s[1] + v2*s[2] + v3*s[3]);
  float pd = wsum64(v0*d[0] + v1*d[1] + v2*d[2] + v3*d[3]);
  if (l == 0){ as2[i] = ps; ad2[i] = pd; }
}

// ---------------- softmax stats + normalized weights ----------------
// conv1: 4 heads. wave per node; self-loop is a regular slot.
__global__ __launch_bounds__(64) void k_stats1(
    const float* __restrict__ as1, const float* __restrict__ ad1,
    const int* __restrict__ rowptr, const int* __restrict__ csrc,
    float* __restrict__ wgt, int n)
{
  int i = blockIdx.x;
  int l = threadIdx.x;
  int beg = rowptr[i], end = rowptr[i+1];
  f32x4 ad4 = *(const f32x4*)(ad1 + 4*i);

  f32x4 m = (f32x4)(-1e30f), s = (f32x4)(0.f);
  for (int sl = beg + l; sl < end; sl += 64){
    int sj = csrc[sl];
    f32x4 a4 = *(const f32x4*)(as1 + 4*sj);
    f32x4 al;
    #pragma unroll
    for (int h = 0; h < 4; ++h){
      float a = lrelu(a4[h] + ad4[h]);
      al[h] = a;
      if (a <= m[h]) s[h] += expf(a - m[h]);
      else { s[h] = s[h]*expf(m[h] - a) + 1.f; m[h] = a; }
    }
    *(f32x4*)(wgt + 4*(size_t)sl) = al;
  }
  f32x4 M2, rd;
  #pragma unroll
  for (int h = 0; h < 4; ++h){
    float M = wmax64(m[h]);
    float S = wsum64(s[h] * expf(m[h] - M));
    M2[h] = M;
    rd[h] = 1.f / (S + 1e-16f);
  }
  for (int sl = beg + l; sl < end; sl += 64){
    f32x4 a = *(const f32x4*)(wgt + 4*(size_t)sl);
    #pragma unroll
    for (int h = 0; h < 4; ++h) a[h] = expf(a[h] - M2[h]) * rd[h];
    *(f32x4*)(wgt + 4*(size_t)sl) = a;
  }
}

// conv2: 1 head
__global__ __launch_bounds__(64) void k_stats2(
    const float* __restrict__ as2, const float* __restrict__ ad2,
    const int* __restrict__ rowptr, const int* __restrict__ csrc,
    float* __restrict__ wgt, int n)
{
  int i = blockIdx.x;
  int l = threadIdx.x;
  int beg = rowptr[i], end = rowptr[i+1];
  float adv = ad2[i];
  float m = -1e30f, s = 0.f;
  for (int sl = beg + l; sl < end; sl += 64){
    float a = lrelu(as2[csrc[sl]] + adv);
    wgt[sl] = a;
    if (a <= m) s += expf(a - m);
    else { s = s*expf(m - a) + 1.f; m = a; }
  }
  float M = wmax64(m);
  float S = wsum64(s * expf(m - M));
  float rd = 1.f / (S + 1e-16f);
  for (int sl = beg + l; sl < end; sl += 64)
    wgt[sl] = expf(wgt[sl] - M) * rd;
}

// ---------------- conv1 aggregate: wave per node, full 256B row, 2-edge unroll --
__global__ __launch_bounds__(64) void k_gagg1(
    const ushort* __restrict__ xb, const float* __restrict__ wgt,
    const int* __restrict__ rowptr, const int* __restrict__ csrc,
    ushort* __restrict__ xagg, int n)
{
  int i = blockIdx.x;
  int l = threadIdx.x;
  int beg = rowptr[i], end = rowptr[i+1];
  float acc0[4] = {0.f,0.f,0.f,0.f};
  float acc1[4] = {0.f,0.f,0.f,0.f};

  int e = beg;
  for (; e + 1 < end; e += 2){
    int s0 = csrc[e], s1 = csrc[e+1];
    f32x4 w0 = *(const f32x4*)(wgt + 4*(size_t)e);
    f32x4 w1 = *(const f32x4*)(wgt + 4*(size_t)(e+1));
    ushort2 u0 = *(const ushort2*)(xb + (size_t)s0*IN_CH + 2*l);
    ushort2 u1 = *(const ushort2*)(xb + (size_t)s1*IN_CH + 2*l);
    float a0 = b2f(u0.x), b0 = b2f(u0.y);
    float a1 = b2f(u1.x), b1 = b2f(u1.y);
    #pragma unroll
    for (int h = 0; h < 4; ++h){
      acc0[h] += w0[h]*a0 + w1[h]*a1;
      acc1[h] += w0[h]*b0 + w1[h]*b1;
    }
  }
  if (e < end){
    int s0 = csrc[e];
    f32x4 w0 = *(const f32x4*)(wgt + 4*(size_t)e);
    ushort2 u0 = *(const ushort2*)(xb + (size_t)s0*IN_CH + 2*l);
    float a0 = b2f(u0.x), b0 = b2f(u0.y);
    #pragma unroll
    for (int h = 0; h < 4; ++h){
      acc0[h] += w0[h]*a0;
      acc1[h] += w0[h]*b0;
    }
  }
  #pragma unroll
  for (int h = 0; h < 4; ++h){
    ushort2 o; o.x = f2b(acc0[h]); o.y = f2b(acc1[h]);
    *(ushort2*)(xagg + (size_t)i*512 + h*128 + 2*l) = o;
  }
}

// ---------------- conv2 aggregate: 2 channel-slab passes, slab L2-resident ----
// slab PASS: contiguous [n][32] table at h2s + PASS*n*32
template<int PASS>
__global__ __launch_bounds__(64) void k_gagg2(
    const ushort* __restrict__ h2s, const float* __restrict__ wgt,
    const int* __restrict__ rowptr, const int* __restrict__ csrc,
    const float* __restrict__ bias, ushort* __restrict__ z2s, int n)
{
  int i = blockIdx.x;
  int l = threadIdx.x;
  int half = l >> 5, ch = l & 31;
  int beg = rowptr[i], end = rowptr[i+1];
  const ushort* tab = h2s + (size_t)PASS*n*32;
  float acc = 0.f;
  for (int sl = beg + half; sl < end; sl += 2){
    int src = __builtin_nontemporal_load(csrc + sl);
    float w = __builtin_nontemporal_load(wgt + sl);
    acc += w * b2f(tab[(size_t)src*32 + ch]);
  }
  acc += __shfl_xor(acc, 32, 64);
  if (half == 0)
    z2s[(size_t)PASS*n*32 + (size_t)i*32 + ch] = f2b(acc + bias[PASS*32 + ch]);
}

// ---------------- bf16 MFMA GEMM, BM=128, BN=64, BK=64, strided, batched-z ----
// SPLITC: write C as two contiguous [sM][32] slabs (col>>5 selects slab).
template<bool RELU_BIAS, bool SPLITC>
__global__ __launch_bounds__(256) void k_gemm2(
    const ushort* __restrict__ A, const ushort* __restrict__ Bt,
    ushort* __restrict__ Cb, const float* __restrict__ bias,
    int M, int K, int lda, int ldc, int aZ, int bZ, int cZ, int sM)
{
  constexpr int BM = 128, BN = 64, NF = 2;
  __shared__ uint4 As[BM*8];
  __shared__ uint4 Bs[BN*8];
  int tid = threadIdx.x;
  int wave = tid >> 6, lane = tid & 63;
  int wr = wave >> 1, wc = wave & 1;
  int bm = blockIdx.y * BM;
  int z = blockIdx.z;
  const ushort* Az = A + (size_t)z*aZ;
  const ushort* Bz = Bt + (size_t)z*bZ;
  int g = lane >> 4, lr = lane & 15;

  f32x4 acc[4][NF];
  #pragma unroll
  for (int m = 0; m < 4; ++m)
    #pragma unroll
    for (int n = 0; n < NF; ++n) acc[m][n] = (f32x4)(0.f);

  for (int k0 = 0; k0 < K; k0 += 64){
    for (int idx = tid; idx < BM*8; idx += 256){
      int r = idx >> 3, c = idx & 7;
      int gr = bm + r;
      uint4 v = make_uint4(0u,0u,0u,0u);
      if (gr < M) v = *(const uint4*)(Az + (size_t)gr*lda + k0 + c*8);
      As[r*8 + (c ^ (r & 7))] = v;
    }
    for (int idx = tid; idx < BN*8; idx += 256){
      int r = idx >> 3, c = idx & 7;
      uint4 v = *(const uint4*)(Bz + (size_t)r*K + k0 + c*8);
      Bs[r*8 + (c ^ (r & 7))] = v;
    }
    __syncthreads();
    #pragma unroll
    for (int kk = 0; kk < 2; ++kk){
      short8v af[4], bf[NF];
      #pragma unroll
      for (int m = 0; m < 4; ++m){
        int r = wr*64 + m*16 + lr;
        int c = kk*4 + g;
        af[m] = *(const short8v*)&As[r*8 + (c ^ (r & 7))];
      }
      #pragma unroll
      for (int n = 0; n < NF; ++n){
        int r = wc*32 + n*16 + lr;
        int c = kk*4 + g;
        bf[n] = *(const short8v*)&Bs[r*8 + (c ^ (r & 7))];
      }
      #pragma unroll
      for (int m = 0; m < 4; ++m)
        #pragma unroll
        for (int n = 0; n < NF; ++n)
          acc[m][n] = __builtin_amdgcn_mfma_f32_16x16x32_bf16(af[m], bf[n], acc[m][n], 0, 0, 0);
    }
    __syncthreads();
  }
  #pragma unroll
  for (int m = 0; m < 4; ++m){
    #pragma unroll
    for (int q = 0; q < 4; ++q){
      int row = bm + wr*64 + m*16 + g*4 + q;
      if (row < M){
        #pragma unroll
        for (int n = 0; n < NF; ++n){
          int col = wc*32 + n*16 + lr;
          float v = acc[m][n][q];
          if (RELU_BIAS) v = fmaxf(v + bias[cZ*z + col], 0.f);
          if (SPLITC)
            Cb[(size_t)(col >> 5)*sM*32 + (size_t)row*32 + (col & 31)] = f2b(v);
          else
            Cb[(size_t)row*ldc + cZ*z + col] = f2b(v);
        }
      }
    }
  }
}

// ---------------- decoder: 2 slab passes, 8 lanes/edge, nt streams ----------------
template<int PASS>
__global__ void k_dec(const ushort* __restrict__ z2s, const int* __restrict__ pos,
                      const int* __restrict__ neg, float* __restrict__ part,
                      float* __restrict__ out, int e, int n){
  int g = blockIdx.x*256 + threadIdx.x;
  int k = g >> 3;
  int sub = g & 7;
  if (k >= 2*e) return;
  int a, b;
  if (k < e){
    a = __builtin_nontemporal_load(pos + k);
    b = __builtin_nontemporal_load(pos + e + k);
  } else {
    int kk = k - e;
    a = __builtin_nontemporal_load(neg + kk);
    b = __builtin_nontemporal_load(neg + e + kk);
  }
  const ushort* tab = z2s + (size_t)PASS*n*32;
  ushort4 ua = *(const ushort4*)(tab + (size_t)a*32 + sub*4);
  ushort4 ub = *(const ushort4*)(tab + (size_t)b*32 + sub*4);
  float p = b2f(ua.x)*b2f(ub.x) + b2f(ua.y)*b2f(ub.y)
          + b2f(ua.z)*b2f(ub.z) + b2f(ua.w)*b2f(ub.w);
  p += __shfl_xor(p, 4, 64);
  p += __shfl_xor(p, 2, 64);
  p += __shfl_xor(p, 1, 64);
  if (sub == 0){
    if (PASS == 0){
      __builtin_nontemporal_store(p, part + k);
    } else {
      float q = __builtin_nontemporal_load(part + k);
      __builtin_nontemporal_store(p + q, out + k);
    }
  }
}

extern "C" void kernel_launch(void* const* d_in, const int* in_sizes, int n_in,
                              void* d_out, int out_size, void* d_ws, size_t ws_size,
                              hipStream_t stream) {
  const float* x        = (const float*)d_in[0];
  const int*   pos      = (const int*)d_in[1];
  const int*   neg      = (const int*)d_in[2];
  const float* W1       = (const float*)d_in[3];
  const float* att_src1 = (const float*)d_in[4];
  const float* att_dst1 = (const float*)d_in[5];
  const float* b1       = (const float*)d_in[6];
  const float* W2       = (const float*)d_in[7];
  const float* att_src2 = (const float*)d_in[8];
  const float* att_dst2 = (const float*)d_in[9];
  const float* b2       = (const float*)d_in[10];
  float* out = (float*)d_out;

  const int N = in_sizes[0] / IN_CH;   // 50000
  const int E = in_sizes[1] / 2;       // 800000
  const int NNZ = E + N;               // edges + self-loops

  char* w = (char*)d_ws;
  ushort* xb   = (ushort*)w;  w += (size_t)N*IN_CH*2;
  ushort* xagg = (ushort*)w;  w += (size_t)N*512*2;          // 51.2MB; sub-reused below
  ushort* z1b  = (ushort*)w;  w += (size_t)N*C1*2;
  float* wgt   = (float*)w;   w += (size_t)NNZ*4*4;          // conv1 4-head weights; reused conv2
  float* as1   = (float*)w;   w += (size_t)N*4*4;
  float* ad1   = (float*)w;   w += (size_t)N*4*4;
  float* as2   = (float*)w;   w += (size_t)N*4;
  float* ad2   = (float*)w;   w += (size_t)N*4;
  ushort* W1t  = (ushort*)w;  w += (size_t)C1*IN_CH*2;
  ushort* W2t  = (ushort*)w;  w += (size_t)OUT_CH*C1*2;
  float* was4  = (float*)w;   w += 512*4;
  float* wad4  = (float*)w;   w += 512*4;
  float* w2s   = (float*)w;   w += 256*4;
  float* w2d   = (float*)w;   w += 256*4;
  int* deg     = (int*)w;     w += (size_t)N*4;
  int* rowptr  = (int*)w;     w += (size_t)(N+1)*4;
  int* cursor  = (int*)w;     w += (size_t)N*4;
  int* bsum    = (int*)w;     w += (size_t)256*4;
  int* csrc    = (int*)w;     w += (size_t)NNZ*4;

  // sub-allocations inside xagg (region dead after z1 GEMM):
  ushort* h2s  = xagg;                                  // 2 slabs x N*32 = 6.4MB
  ushort* z2s  = xagg + (size_t)2*N*32;                 // 2 slabs x N*32 = 6.4MB
  float*  part = (float*)(xagg + (size_t)4*N*32);       // 2E f32 = 6.4MB

  int eb = (E + 255)/256;
  int nb = (N + 255)/256;
  const int* pdst = pos + E;

  k_init<<<nb, 256, 0, stream>>>(deg, cursor, N);
  k_hist<<<eb, 256, 0, stream>>>(pdst, deg, E);
  k_blocksum<<<nb, 256, 0, stream>>>(deg, bsum, N);
  k_scanb<<<1, 256, 0, stream>>>(bsum, nb);
  k_scanfinal<<<nb, 256, 0, stream>>>(deg, bsum, rowptr, N);
  k_scatter<<<eb, 256, 0, stream>>>(pos, pdst, rowptr, cursor, csrc, E);
  k_self<<<nb, 256, 0, stream>>>(rowptr, csrc, N);

  k_tw<<<(IN_CH*C1 + 255)/256, 256, 0, stream>>>(W1, W1t, IN_CH, C1);
  k_tw<<<(C1*OUT_CH + 255)/256, 256, 0, stream>>>(W2, W2t, C1, OUT_CH);
  k_fold1<<<1, 512, 0, stream>>>(W1, att_src1, att_dst1, was4, wad4);
  k_fold2<<<1, 256, 0, stream>>>(W2, att_src2, att_dst2, w2s, w2d);

  k_fattc<<<N, 64, 0, stream>>>(x, was4, wad4, xb, as1, ad1, N);
  k_stats1<<<N, 64, 0, stream>>>(as1, ad1, rowptr, csrc, wgt, N);
  k_gagg1<<<N, 64, 0, stream>>>(xb, wgt, rowptr, csrc, xagg, N);

  {  // z1 = relu(blockdiag(xagg_h @ W1_h) + b1), 4 heads via blockIdx.z
    dim3 g(1, (N + 127)/128, 4);
    k_gemm2<true, false><<<g, 256, 0, stream>>>(xagg, W1t, z1b, b1,
        N, IN_CH, 512, C1, IN_CH, OUT_CH*IN_CH, OUT_CH, 0);
  }
  k_fatt2<<<N, 64, 0, stream>>>(z1b, w2s, w2d, as2, ad2, N);

  {  // h2 = z1 @ W2, written as two contiguous [N][32] slabs
    dim3 g(1, (N + 127)/128, 1);
    k_gemm2<false, true><<<g, 256, 0, stream>>>(z1b, W2t, h2s, nullptr,
        N, C1, C1, 0, 0, 0, 0, N);
  }
  k_stats2<<<N, 64, 0, stream>>>(as2, ad2, rowptr, csrc, wgt, N);
  k_gagg2<0><<<N, 64, 0, stream>>>(h2s, wgt, rowptr, csrc, b2, z2s, N);
  k_gagg2<1><<<N, 64, 0, stream>>>(h2s, wgt, rowptr, csrc, b2, z2s, N);

  int db = (int)(((size_t)2*E*8 + 255)/256);
  k_dec<0><<<db, 256, 0, stream>>>(z2s, pos, neg, part, out, E, N);
  k_dec<1><<<db, 256, 0, stream>>>(z2s, pos, neg, part, out, E, N);
}

// Round 8
// 369.558 us; speedup vs baseline: 1.3052x; 1.3052x over previous
//
#include <hip/hip_runtime.h>
#include <hip/hip_bf16.h>
#include <math.h>

#define IN_CH 128
#define HID 64
#define HEADS 4
#define C1 (HEADS*HID)   // 256
#define OUT_CH 64

typedef __attribute__((ext_vector_type(8))) short short8v;
typedef __attribute__((ext_vector_type(4))) float f32x4;

__device__ __forceinline__ float lrelu(float x){ return x > 0.f ? x : 0.2f*x; }

__device__ __forceinline__ ushort f2b(float f){
  unsigned u = __builtin_bit_cast(unsigned, f);
  unsigned r = (u + 0x7FFF + ((u>>16)&1)) >> 16;
  return (ushort)r;
}
__device__ __forceinline__ float b2f(ushort b){
  unsigned u = ((unsigned)b) << 16;
  return __builtin_bit_cast(float, u);
}

__device__ __forceinline__ float wsum64(float v){
  #pragma unroll
  for (int m = 32; m >= 1; m >>= 1) v += __shfl_xor(v, m, 64);
  return v;
}
__device__ __forceinline__ float wmax64(float v){
  #pragma unroll
  for (int m = 32; m >= 1; m >>= 1) v = fmaxf(v, __shfl_xor(v, m, 64));
  return v;
}

// dot of 2 packed bf16 pairs
__device__ __forceinline__ float dot2(unsigned ua, unsigned ub){
  float la = __builtin_bit_cast(float, ua << 16);
  float ha = __builtin_bit_cast(float, ua & 0xFFFF0000u);
  float lb = __builtin_bit_cast(float, ub << 16);
  float hb = __builtin_bit_cast(float, ub & 0xFFFF0000u);
  return la*lb + ha*hb;
}

// ---------------- CSR build (self-loops included as slots) ----------------

__global__ void k_init(int* deg, int* cur, int n){
  int i = blockIdx.x*256 + threadIdx.x;
  if (i < n){ deg[i] = 1; cur[i] = 0; }   // deg starts at 1: self-loop slot
}

__global__ void k_hist(const int* __restrict__ dst, int* deg, int e){
  int i = blockIdx.x*256 + threadIdx.x;
  if (i < e) atomicAdd(&deg[dst[i]], 1);
}

__global__ void k_blocksum(const int* __restrict__ deg, int* bsum, int n){
  __shared__ int buf[256];
  int b = blockIdx.x, tid = threadIdx.x;
  int i = b*256 + tid;
  buf[tid] = (i < n) ? deg[i] : 0;
  __syncthreads();
  for (int off = 128; off > 0; off >>= 1){
    if (tid < off) buf[tid] += buf[tid + off];
    __syncthreads();
  }
  if (tid == 0) bsum[b] = buf[0];
}

__global__ void k_scanb(int* bsum, int nb){
  __shared__ int buf[256];
  int tid = threadIdx.x;
  int v = (tid < nb) ? bsum[tid] : 0;
  buf[tid] = v;
  __syncthreads();
  for (int off = 1; off < 256; off <<= 1){
    int t = (tid >= off) ? buf[tid - off] : 0;
    __syncthreads();
    buf[tid] += t;
    __syncthreads();
  }
  if (tid < nb) bsum[tid] = buf[tid] - v;
}

__global__ void k_scanfinal(const int* __restrict__ deg, const int* __restrict__ bsum,
                            int* rowptr, int n){
  __shared__ int buf[256];
  int b = blockIdx.x, tid = threadIdx.x;
  int i = b*256 + tid;
  int v = (i < n) ? deg[i] : 0;
  buf[tid] = v;
  __syncthreads();
  for (int off = 1; off < 256; off <<= 1){
    int t = (tid >= off) ? buf[tid - off] : 0;
    __syncthreads();
    buf[tid] += t;
    __syncthreads();
  }
  if (i < n) rowptr[i + 1] = bsum[b] + buf[tid];
  if (b == 0 && tid == 0) rowptr[0] = 0;
}

__global__ void k_scatter(const int* __restrict__ src, const int* __restrict__ dst,
                          const int* __restrict__ rowptr, int* cursor, int* csrc, int e){
  int i = blockIdx.x*256 + threadIdx.x;
  if (i < e){
    int d = dst[i];
    int slot = rowptr[d] + atomicAdd(&cursor[d], 1);
    csrc[slot] = src[i];
  }
}

__global__ void k_self(const int* __restrict__ rowptr, int* csrc, int n){
  int i = blockIdx.x*256 + threadIdx.x;
  if (i < n) csrc[rowptr[i+1] - 1] = i;   // self-loop in last slot
}

// ---------------- weight folds ----------------

// W [K][N] f32 -> Wt [N][K] bf16
__global__ void k_tw(const float* __restrict__ W, ushort* __restrict__ Wt, int K, int N){
  int i = blockIdx.x*256 + threadIdx.x;
  if (i < K*N){
    int k = i / N, c = i - k*N;
    Wt[(size_t)c*K + k] = f2b(W[i]);
  }
}

__global__ void k_fold1(const float* __restrict__ W1, const float* __restrict__ as_v,
                        const float* __restrict__ ad_v, float* was4, float* wad4){
  int tid = threadIdx.x;           // 0..511 = c*4+h
  int c = tid >> 2, h = tid & 3;
  float s = 0.f, d = 0.f;
  for (int j = 0; j < HID; ++j){
    float w = W1[c*C1 + h*HID + j];
    s += w * as_v[h*HID + j];
    d += w * ad_v[h*HID + j];
  }
  was4[tid] = s; wad4[tid] = d;
}

__global__ void k_fold2(const float* __restrict__ W2, const float* __restrict__ as_v,
                        const float* __restrict__ ad_v, float* w2s, float* w2d){
  int c = threadIdx.x;             // 0..255
  float s = 0.f, d = 0.f;
  for (int o = 0; o < OUT_CH; ++o){
    float w = W2[c*OUT_CH + o];
    s += w * as_v[o];
    d += w * ad_v[o];
  }
  w2s[c] = s; w2d[c] = d;
}

// fused: cast x->bf16 + conv1 attention scores. wave per node, lane = 2 channels.
__global__ __launch_bounds__(64) void k_fattc(const float* __restrict__ x,
    const float* __restrict__ was4, const float* __restrict__ wad4,
    ushort* __restrict__ xb, float* __restrict__ as1, float* __restrict__ ad1, int n){
  int i = blockIdx.x;
  int l = threadIdx.x;
  float2 u = *(const float2*)(x + (size_t)i*IN_CH + 2*l);
  ushort2 o; o.x = f2b(u.x); o.y = f2b(u.y);
  *(ushort2*)(xb + (size_t)i*IN_CH + 2*l) = o;
  float v0 = u.x, v1 = u.y;
  f32x4 s0 = *(const f32x4*)(was4 + 8*l);
  f32x4 s1 = *(const f32x4*)(was4 + 8*l + 4);
  f32x4 d0 = *(const f32x4*)(wad4 + 8*l);
  f32x4 d1 = *(const f32x4*)(wad4 + 8*l + 4);
  f32x4 ps, pd;
  #pragma unroll
  for (int h = 0; h < 4; ++h){
    ps[h] = wsum64(v0*s0[h] + v1*s1[h]);
    pd[h] = wsum64(v0*d0[h] + v1*d1[h]);
  }
  if (l == 0){
    *(f32x4*)(as1 + 4*i) = ps;
    *(f32x4*)(ad1 + 4*i) = pd;
  }
}

// as2/ad2 from z1: wave per node, lane = 4 channels
__global__ __launch_bounds__(64) void k_fatt2(const ushort* __restrict__ z1b,
    const float* __restrict__ w2s, const float* __restrict__ w2d,
    float* __restrict__ as2, float* __restrict__ ad2, int n){
  int i = blockIdx.x;
  int l = threadIdx.x;
  ushort4 u = *(const ushort4*)(z1b + (size_t)i*C1 + 4*l);
  float v0 = b2f(u.x), v1 = b2f(u.y), v2 = b2f(u.z), v3 = b2f(u.w);
  f32x4 s = *(const f32x4*)(w2s + 4*l);
  f32x4 d = *(const f32x4*)(w2d + 4*l);
  float ps = wsum64(v0*s[0] + v1*s[1] + v2*s[2] + v3*s[3]);
  float pd = wsum64(v0*d[0] + v1*d[1] + v2*d[2] + v3*d[3]);
  if (l == 0){ as2[i] = ps; ad2[i] = pd; }
}

// ---------------- softmax stats + normalized weights ----------------
// conv1: 4 heads. wave per node; self-loop is a regular slot.
__global__ __launch_bounds__(64) void k_stats1(
    const float* __restrict__ as1, const float* __restrict__ ad1,
    const int* __restrict__ rowptr, const int* __restrict__ csrc,
    float* __restrict__ wgt, int n)
{
  int i = blockIdx.x;
  int l = threadIdx.x;
  int beg = rowptr[i], end = rowptr[i+1];
  f32x4 ad4 = *(const f32x4*)(ad1 + 4*i);

  f32x4 m = (f32x4)(-1e30f), s = (f32x4)(0.f);
  for (int sl = beg + l; sl < end; sl += 64){
    int sj = csrc[sl];
    f32x4 a4 = *(const f32x4*)(as1 + 4*sj);
    f32x4 al;
    #pragma unroll
    for (int h = 0; h < 4; ++h){
      float a = lrelu(a4[h] + ad4[h]);
      al[h] = a;
      if (a <= m[h]) s[h] += expf(a - m[h]);
      else { s[h] = s[h]*expf(m[h] - a) + 1.f; m[h] = a; }
    }
    *(f32x4*)(wgt + 4*(size_t)sl) = al;
  }
  f32x4 M2, rd;
  #pragma unroll
  for (int h = 0; h < 4; ++h){
    float M = wmax64(m[h]);
    float S = wsum64(s[h] * expf(m[h] - M));
    M2[h] = M;
    rd[h] = 1.f / (S + 1e-16f);
  }
  for (int sl = beg + l; sl < end; sl += 64){
    f32x4 a = *(const f32x4*)(wgt + 4*(size_t)sl);
    #pragma unroll
    for (int h = 0; h < 4; ++h) a[h] = expf(a[h] - M2[h]) * rd[h];
    *(f32x4*)(wgt + 4*(size_t)sl) = a;
  }
}

// conv2: 1 head
__global__ __launch_bounds__(64) void k_stats2(
    const float* __restrict__ as2, const float* __restrict__ ad2,
    const int* __restrict__ rowptr, const int* __restrict__ csrc,
    float* __restrict__ wgt, int n)
{
  int i = blockIdx.x;
  int l = threadIdx.x;
  int beg = rowptr[i], end = rowptr[i+1];
  float adv = ad2[i];
  float m = -1e30f, s = 0.f;
  for (int sl = beg + l; sl < end; sl += 64){
    float a = lrelu(as2[csrc[sl]] + adv);
    wgt[sl] = a;
    if (a <= m) s += expf(a - m);
    else { s = s*expf(m - a) + 1.f; m = a; }
  }
  float M = wmax64(m);
  float S = wsum64(s * expf(m - M));
  float rd = 1.f / (S + 1e-16f);
  for (int sl = beg + l; sl < end; sl += 64)
    wgt[sl] = expf(wgt[sl] - M) * rd;
}

// ---------------- conv1 aggregate: wave per node, full 256B row, 2-edge unroll --
__global__ __launch_bounds__(64) void k_gagg1(
    const ushort* __restrict__ xb, const float* __restrict__ wgt,
    const int* __restrict__ rowptr, const int* __restrict__ csrc,
    ushort* __restrict__ xagg, int n)
{
  int i = blockIdx.x;
  int l = threadIdx.x;
  int beg = rowptr[i], end = rowptr[i+1];
  float acc0[4] = {0.f,0.f,0.f,0.f};
  float acc1[4] = {0.f,0.f,0.f,0.f};

  int e = beg;
  for (; e + 1 < end; e += 2){
    int s0 = csrc[e], s1 = csrc[e+1];
    f32x4 w0 = *(const f32x4*)(wgt + 4*(size_t)e);
    f32x4 w1 = *(const f32x4*)(wgt + 4*(size_t)(e+1));
    ushort2 u0 = *(const ushort2*)(xb + (size_t)s0*IN_CH + 2*l);
    ushort2 u1 = *(const ushort2*)(xb + (size_t)s1*IN_CH + 2*l);
    float a0 = b2f(u0.x), b0 = b2f(u0.y);
    float a1 = b2f(u1.x), b1 = b2f(u1.y);
    #pragma unroll
    for (int h = 0; h < 4; ++h){
      acc0[h] += w0[h]*a0 + w1[h]*a1;
      acc1[h] += w0[h]*b0 + w1[h]*b1;
    }
  }
  if (e < end){
    int s0 = csrc[e];
    f32x4 w0 = *(const f32x4*)(wgt + 4*(size_t)e);
    ushort2 u0 = *(const ushort2*)(xb + (size_t)s0*IN_CH + 2*l);
    float a0 = b2f(u0.x), b0 = b2f(u0.y);
    #pragma unroll
    for (int h = 0; h < 4; ++h){
      acc0[h] += w0[h]*a0;
      acc1[h] += w0[h]*b0;
    }
  }
  #pragma unroll
  for (int h = 0; h < 4; ++h){
    ushort2 o; o.x = f2b(acc0[h]); o.y = f2b(acc1[h]);
    *(ushort2*)(xagg + (size_t)i*512 + h*128 + 2*l) = o;
  }
}

// ---------------- conv2 aggregate: wave per node, 2 halves = 2 edges in flight --
__global__ __launch_bounds__(64) void k_gagg2(
    const ushort* __restrict__ h2b, const float* __restrict__ wgt,
    const int* __restrict__ rowptr, const int* __restrict__ csrc,
    const float* __restrict__ bias, ushort* __restrict__ z2b, int n)
{
  int i = blockIdx.x;
  int l = threadIdx.x;
  int half = l >> 5;
  int c2 = (l & 31) * 2;
  int beg = rowptr[i], end = rowptr[i+1];
  float acc0 = 0.f, acc1 = 0.f;
  for (int sl = beg + half; sl < end; sl += 2){
    int src = csrc[sl];
    float w = wgt[sl];
    ushort2 u = *(const ushort2*)(h2b + (size_t)src*OUT_CH + c2);
    acc0 += w * b2f(u.x);
    acc1 += w * b2f(u.y);
  }
  acc0 += __shfl_xor(acc0, 32, 64);
  acc1 += __shfl_xor(acc1, 32, 64);
  if (half == 0){
    ushort2 o;
    o.x = f2b(acc0 + bias[c2]);
    o.y = f2b(acc1 + bias[c2+1]);
    *(ushort2*)(z2b + (size_t)i*OUT_CH + c2) = o;
  }
}

// ---------------- bf16 MFMA GEMM, BM=128, BN=64, BK=64, strided, batched-z ----
template<bool RELU_BIAS>
__global__ __launch_bounds__(256) void k_gemm2(
    const ushort* __restrict__ A, const ushort* __restrict__ Bt,
    ushort* __restrict__ Cb, const float* __restrict__ bias,
    int M, int K, int lda, int ldc, int aZ, int bZ, int cZ)
{
  constexpr int BM = 128, BN = 64, NF = 2;
  __shared__ uint4 As[BM*8];
  __shared__ uint4 Bs[BN*8];
  int tid = threadIdx.x;
  int wave = tid >> 6, lane = tid & 63;
  int wr = wave >> 1, wc = wave & 1;
  int bm = blockIdx.y * BM;
  int z = blockIdx.z;
  const ushort* Az = A + (size_t)z*aZ;
  const ushort* Bz = Bt + (size_t)z*bZ;
  int g = lane >> 4, lr = lane & 15;

  f32x4 acc[4][NF];
  #pragma unroll
  for (int m = 0; m < 4; ++m)
    #pragma unroll
    for (int n = 0; n < NF; ++n) acc[m][n] = (f32x4)(0.f);

  for (int k0 = 0; k0 < K; k0 += 64){
    for (int idx = tid; idx < BM*8; idx += 256){
      int r = idx >> 3, c = idx & 7;
      int gr = bm + r;
      uint4 v = make_uint4(0u,0u,0u,0u);
      if (gr < M) v = *(const uint4*)(Az + (size_t)gr*lda + k0 + c*8);
      As[r*8 + (c ^ (r & 7))] = v;
    }
    for (int idx = tid; idx < BN*8; idx += 256){
      int r = idx >> 3, c = idx & 7;
      uint4 v = *(const uint4*)(Bz + (size_t)r*K + k0 + c*8);
      Bs[r*8 + (c ^ (r & 7))] = v;
    }
    __syncthreads();
    #pragma unroll
    for (int kk = 0; kk < 2; ++kk){
      short8v af[4], bf[NF];
      #pragma unroll
      for (int m = 0; m < 4; ++m){
        int r = wr*64 + m*16 + lr;
        int c = kk*4 + g;
        af[m] = *(const short8v*)&As[r*8 + (c ^ (r & 7))];
      }
      #pragma unroll
      for (int n = 0; n < NF; ++n){
        int r = wc*32 + n*16 + lr;
        int c = kk*4 + g;
        bf[n] = *(const short8v*)&Bs[r*8 + (c ^ (r & 7))];
      }
      #pragma unroll
      for (int m = 0; m < 4; ++m)
        #pragma unroll
        for (int n = 0; n < NF; ++n)
          acc[m][n] = __builtin_amdgcn_mfma_f32_16x16x32_bf16(af[m], bf[n], acc[m][n], 0, 0, 0);
    }
    __syncthreads();
  }
  #pragma unroll
  for (int m = 0; m < 4; ++m){
    #pragma unroll
    for (int q = 0; q < 4; ++q){
      int row = bm + wr*64 + m*16 + g*4 + q;
      if (row < M){
        #pragma unroll
        for (int n = 0; n < NF; ++n){
          int col = wc*32 + n*16 + lr;
          float v = acc[m][n][q];
          if (RELU_BIAS) v = fmaxf(v + bias[cZ*z + col], 0.f);
          Cb[(size_t)row*ldc + cZ*z + col] = f2b(v);
        }
      }
    }
  }
}

// ---------------- decoder: 8 lanes/edge, 16B loads, single pass ----------------
__global__ void k_decode(const ushort* __restrict__ z2b, const int* __restrict__ pos,
                         const int* __restrict__ neg, float* __restrict__ out, int e){
  int g = blockIdx.x*256 + threadIdx.x;
  int k = g >> 3;
  int sub = g & 7;
  if (k >= 2*e) return;
  int a, b;
  if (k < e){
    a = __builtin_nontemporal_load(pos + k);
    b = __builtin_nontemporal_load(pos + e + k);
  } else {
    int kk = k - e;
    a = __builtin_nontemporal_load(neg + kk);
    b = __builtin_nontemporal_load(neg + e + kk);
  }
  uint4 ua = *(const uint4*)(z2b + (size_t)a*OUT_CH + sub*8);
  uint4 ub = *(const uint4*)(z2b + (size_t)b*OUT_CH + sub*8);
  float p = dot2(ua.x, ub.x) + dot2(ua.y, ub.y) + dot2(ua.z, ub.z) + dot2(ua.w, ub.w);
  p += __shfl_xor(p, 4, 64);
  p += __shfl_xor(p, 2, 64);
  p += __shfl_xor(p, 1, 64);
  if (sub == 0) __builtin_nontemporal_store(p, out + k);
}

extern "C" void kernel_launch(void* const* d_in, const int* in_sizes, int n_in,
                              void* d_out, int out_size, void* d_ws, size_t ws_size,
                              hipStream_t stream) {
  const float* x        = (const float*)d_in[0];
  const int*   pos      = (const int*)d_in[1];
  const int*   neg      = (const int*)d_in[2];
  const float* W1       = (const float*)d_in[3];
  const float* att_src1 = (const float*)d_in[4];
  const float* att_dst1 = (const float*)d_in[5];
  const float* b1       = (const float*)d_in[6];
  const float* W2       = (const float*)d_in[7];
  const float* att_src2 = (const float*)d_in[8];
  const float* att_dst2 = (const float*)d_in[9];
  const float* b2       = (const float*)d_in[10];
  float* out = (float*)d_out;

  const int N = in_sizes[0] / IN_CH;   // 50000
  const int E = in_sizes[1] / 2;       // 800000
  const int NNZ = E + N;               // edges + self-loops

  char* w = (char*)d_ws;
  ushort* xb   = (ushort*)w;  w += (size_t)N*IN_CH*2;
  ushort* xagg = (ushort*)w;  w += (size_t)N*512*2;          // 51.2MB; sub-reused below
  ushort* z1b  = (ushort*)w;  w += (size_t)N*C1*2;
  float* wgt   = (float*)w;   w += (size_t)NNZ*4*4;          // conv1 4-head weights; reused conv2
  float* as1   = (float*)w;   w += (size_t)N*4*4;
  float* ad1   = (float*)w;   w += (size_t)N*4*4;
  float* as2   = (float*)w;   w += (size_t)N*4;
  float* ad2   = (float*)w;   w += (size_t)N*4;
  ushort* W1t  = (ushort*)w;  w += (size_t)C1*IN_CH*2;
  ushort* W2t  = (ushort*)w;  w += (size_t)OUT_CH*C1*2;
  float* was4  = (float*)w;   w += 512*4;
  float* wad4  = (float*)w;   w += 512*4;
  float* w2s   = (float*)w;   w += 256*4;
  float* w2d   = (float*)w;   w += 256*4;
  int* deg     = (int*)w;     w += (size_t)N*4;
  int* rowptr  = (int*)w;     w += (size_t)(N+1)*4;
  int* cursor  = (int*)w;     w += (size_t)N*4;
  int* bsum    = (int*)w;     w += (size_t)256*4;
  int* csrc    = (int*)w;     w += (size_t)NNZ*4;

  // sub-allocations inside xagg (region dead after z1 GEMM):
  ushort* h2b = xagg;                                  // 6.4MB
  ushort* z2b = xagg + (size_t)N*OUT_CH;               // 6.4MB

  int eb = (E + 255)/256;
  int nb = (N + 255)/256;
  const int* pdst = pos + E;

  k_init<<<nb, 256, 0, stream>>>(deg, cursor, N);
  k_hist<<<eb, 256, 0, stream>>>(pdst, deg, E);
  k_blocksum<<<nb, 256, 0, stream>>>(deg, bsum, N);
  k_scanb<<<1, 256, 0, stream>>>(bsum, nb);
  k_scanfinal<<<nb, 256, 0, stream>>>(deg, bsum, rowptr, N);
  k_scatter<<<eb, 256, 0, stream>>>(pos, pdst, rowptr, cursor, csrc, E);
  k_self<<<nb, 256, 0, stream>>>(rowptr, csrc, N);

  k_tw<<<(IN_CH*C1 + 255)/256, 256, 0, stream>>>(W1, W1t, IN_CH, C1);
  k_tw<<<(C1*OUT_CH + 255)/256, 256, 0, stream>>>(W2, W2t, C1, OUT_CH);
  k_fold1<<<1, 512, 0, stream>>>(W1, att_src1, att_dst1, was4, wad4);
  k_fold2<<<1, 256, 0, stream>>>(W2, att_src2, att_dst2, w2s, w2d);

  k_fattc<<<N, 64, 0, stream>>>(x, was4, wad4, xb, as1, ad1, N);
  k_stats1<<<N, 64, 0, stream>>>(as1, ad1, rowptr, csrc, wgt, N);
  k_gagg1<<<N, 64, 0, stream>>>(xb, wgt, rowptr, csrc, xagg, N);

  {  // z1 = relu(blockdiag(xagg_h @ W1_h) + b1), 4 heads via blockIdx.z
    dim3 g(1, (N + 127)/128, 4);
    k_gemm2<true><<<g, 256, 0, stream>>>(xagg, W1t, z1b, b1,
        N, IN_CH, 512, C1, IN_CH, OUT_CH*IN_CH, OUT_CH);
  }
  k_fatt2<<<N, 64, 0, stream>>>(z1b, w2s, w2d, as2, ad2, N);

  {  // h2 = z1 @ W2
    dim3 g(1, (N + 127)/128, 1);
    k_gemm2<false><<<g, 256, 0, stream>>>(z1b, W2t, h2b, nullptr,
        N, C1, C1, OUT_CH, 0, 0, 0);
  }
  k_stats2<<<N, 64, 0, stream>>>(as2, ad2, rowptr, csrc, wgt, N);
  k_gagg2<<<N, 64, 0, stream>>>(h2b, wgt, rowptr, csrc, b2, z2b, N);

  int db = (int)(((size_t)2*E*8 + 255)/256);
  k_decode<<<db, 256, 0, stream>>>(z2b, pos, neg, out, E);
}